// Round 4
// baseline (236.853 us; speedup 1.0000x reference)
//
#include <hip/hip_runtime.h>

#define HW    512
#define OUTW  128
#define NIMG  96                          // 32*3
#define N_HR  ((long long)NIMG*HW*HW)     // 25165824
#define N_LR  ((long long)NIMG*OUTW*OUTW) // 1572864
#define NB1   (NIMG*HW/4)                 // 12288 k1 blocks (4 rows each)
#define NB2   (NIMG*OUTW/4)               // 3072  k2 blocks (4 out rows each)

// PyTorch bicubic kernel, a = -0.75
__device__ __forceinline__ float cubic075(float x){
    float ax = fabsf(x);
    float ax2 = ax*ax, ax3 = ax2*ax;
    const float A = -0.75f;
    float f1 = (A+2.f)*ax3 - (A+3.f)*ax2 + 1.f;
    float f2 = A*ax3 - 5.f*A*ax2 + 8.f*A*ax - 4.f*A;
    return ax <= 1.f ? f1 : (ax < 2.f ? f2 : 0.f);
}

// scale=4 antialiased window: 16 taps, dist=(k-7.5)/4, normalized.
// Shift-invariant across all output positions (absmax=0.0 in R1-R3).
// All inputs are compile-time constants -> folds to 16 immediates at -O3.
__device__ __forceinline__ void get_weights(float w[16]){
    float s = 0.f;
#pragma unroll
    for (int k = 0; k < 16; ++k){
        float d = ((float)k - 7.5f) * 0.25f;
        w[k] = cubic075(d);
        s += w[k];
    }
#pragma unroll
    for (int k = 0; k < 16; ++k) w[k] /= s;
}

// k1: one WAVE = one full input row. Loads pred+tgt rows (4 independent
// float4 loads, all issued up front -> max MLP), pix partial, in-register
// shuffle h-filter, 512B tmp store. No loops, no LDS staging.
__global__ __launch_bounds__(256, 8) void k1(const float* __restrict__ pred,
                                             const float* __restrict__ tgt,
                                             float* __restrict__ tmp,
                                             double* __restrict__ part1){
    const int b   = blockIdx.x;
    const int W   = ((b & 7) * (NB1/8)) + (b >> 3);   // XCD-chunked: xcd owns 12 images
    const int img = W >> 7;                           // W / 128
    const int h   = ((W & 127) << 2) + (threadIdx.x >> 6);
    const int l   = threadIdx.x & 63;
    const int wv  = threadIdx.x >> 6;

    const float4* Pr = (const float4*)(pred + ((size_t)img*HW + h)*HW);
    const float4* Tr = (const float4*)(tgt  + ((size_t)img*HW + h)*HW);
    float4 a0 = Pr[2*l], a1 = Pr[2*l+1];
    float4 b0 = Tr[2*l], b1 = Tr[2*l+1];

    float wt[16]; get_weights(wt);

    const float p0=a0.x,p1v=a0.y,p2v=a0.z,p3=a0.w,
                p4=a1.x,p5=a1.y,p6=a1.z,p7=a1.w;

    float pix = fabsf(p0-b0.x)+fabsf(p1v-b0.y)+fabsf(p2v-b0.z)+fabsf(p3-b0.w)
              + fabsf(p4-b1.x)+fabsf(p5-b1.y)+fabsf(p6-b1.z)+fabsf(p7-b1.w);

    // halo cols 8l-6..8l-1 and 8l+8..8l+13 via shuffles
    float Lm6 = __shfl_up(p2v,1,64), Lm5 = __shfl_up(p3,1,64),
          Lm4 = __shfl_up(p4,1,64),  Lm3 = __shfl_up(p5,1,64),
          Lm2 = __shfl_up(p6,1,64),  Lm1 = __shfl_up(p7,1,64);
    float R8  = __shfl_down(p0,1,64), R9  = __shfl_down(p1v,1,64),
          R10 = __shfl_down(p2v,1,64),R11 = __shfl_down(p3,1,64),
          R12 = __shfl_down(p4,1,64), R13 = __shfl_down(p5,1,64);
    if (l == 0){ Lm6=p0; Lm5=p0; Lm4=p0; Lm3=p0; Lm2=p0; Lm1=p0; }
    if (l == 63){ R8=p7; R9=p7; R10=p7; R11=p7; R12=p7; R13=p7; }

    float w20[20] = {Lm6,Lm5,Lm4,Lm3,Lm2,Lm1,p0,p1v,p2v,p3,p4,p5,p6,p7,
                     R8,R9,R10,R11,R12,R13};
    float h0 = 0.f, h1 = 0.f;
#pragma unroll
    for (int k = 0; k < 16; ++k){
        h0 += wt[k]*w20[k];
        h1 += wt[k]*w20[k+4];
    }
    float2 st; st.x = h0; st.y = h1;
    *(float2*)(tmp + ((size_t)img*HW + h)*OUTW + 2*l) = st;

#pragma unroll
    for (int off = 32; off > 0; off >>= 1)
        pix += __shfl_down(pix, off, 64);
    __shared__ double sp[4];
    if (l == 0) sp[wv] = (double)pix;
    __syncthreads();
    if (threadIdx.x == 0) part1[b] = sp[0]+sp[1]+sp[2]+sp[3];
}

// k2: one WAVE = one output row. 16 independent float2 loads from tmp
// (same XCD swizzle as k1 -> L2/L3 local) + lr row, vertical 16-tap, reduce.
__global__ __launch_bounds__(256, 6) void k2(const float* __restrict__ tmp,
                                             const float* __restrict__ lr,
                                             double* __restrict__ part2){
    const int b   = blockIdx.x;
    const int W   = ((b & 7) * (NB2/8)) + (b >> 3);   // same image->XCD map as k1
    const int img = W >> 5;                           // W / 32
    const int o   = ((W & 31) << 2) + (threadIdx.x >> 6);
    const int l   = threadIdx.x & 63;
    const int wv  = threadIdx.x >> 6;

    float wt[16]; get_weights(wt);
    const float* T = tmp + (size_t)img * HW * OUTW;
    const int base = 4*o - 6;

    float2 t[16];
#pragma unroll
    for (int r = 0; r < 16; ++r){
        int y = min(HW-1, max(0, base + r));
        t[r] = *(const float2*)(T + (size_t)y*OUTW + 2*l);
    }
    const float2 lv = *(const float2*)(lr + ((size_t)img*OUTW + o)*OUTW + 2*l);

    float a0 = 0.f, a1 = 0.f;
#pragma unroll
    for (int r = 0; r < 16; ++r){
        a0 += wt[r]*t[r].x;
        a1 += wt[r]*t[r].y;
    }
    float la = fabsf(a0 - lv.x) + fabsf(a1 - lv.y);

#pragma unroll
    for (int off = 32; off > 0; off >>= 1)
        la += __shfl_down(la, off, 64);
    __shared__ double sp[4];
    if (l == 0) sp[wv] = (double)la;
    __syncthreads();
    if (threadIdx.x == 0) part2[b] = sp[0]+sp[1]+sp[2]+sp[3];
}

// finalize: one block, 1024 threads, grid-stride over both partial arrays
__global__ __launch_bounds__(1024) void k3(const double* __restrict__ part1,
                                           const double* __restrict__ part2,
                                           float* __restrict__ out){
    const int t = threadIdx.x;
    double v1 = 0.0, v2 = 0.0;
    for (int i = t; i < NB1; i += 1024) v1 += part1[i];
    for (int i = t; i < NB2; i += 1024) v2 += part2[i];
#pragma unroll
    for (int off = 32; off > 0; off >>= 1){
        v1 += __shfl_down(v1, off, 64);
        v2 += __shfl_down(v2, off, 64);
    }
    __shared__ double s1[16], s2[16];
    const int lane = t & 63, wid = t >> 6;
    if (lane == 0){ s1[wid] = v1; s2[wid] = v2; }
    __syncthreads();
    if (t == 0){
        double S1 = 0.0, S2 = 0.0;
#pragma unroll
        for (int k = 0; k < 16; ++k){ S1 += s1[k]; S2 += s2[k]; }
        float pix     = (float)(S1 / (double)N_HR);
        float lr_term = (float)(S2 / (double)N_LR);
        float pair    = 0.f;
        float consist = 1.0f * lr_term + 1.0f * pair;   // LAM_LR, LAM_PAIR
        float total   = pix + 0.1f * consist;           // LAM_CONSIST
        out[0] = total; out[1] = pix; out[2] = consist; out[3] = lr_term; out[4] = pair;
    }
}

extern "C" void kernel_launch(void* const* d_in, const int* in_sizes, int n_in,
                              void* d_out, int out_size, void* d_ws, size_t ws_size,
                              hipStream_t stream){
    const float* pred = (const float*)d_in[0];
    const float* tgt  = (const float*)d_in[1];
    const float* lrr  = (const float*)d_in[2];
    float* out = (float*)d_out;

    double* part1 = (double*)d_ws;                       // 12288 doubles
    double* part2 = part1 + NB1;                         // 3072 doubles
    float*  tmp   = (float*)((char*)d_ws + 131072);      // 96*512*128 f32 = 25.2 MB

    k1<<<NB1, 256, 0, stream>>>(pred, tgt, tmp, part1);
    k2<<<NB2, 256, 0, stream>>>(tmp, lrr, part2);
    k3<<<1, 1024, 0, stream>>>(part1, part2, out);
}

// Round 5
// 233.036 us; speedup vs baseline: 1.0164x; 1.0164x over previous
//
#include <hip/hip_runtime.h>

#define HW    512
#define OUTW  128
#define NIMG  96                          // 32*3
#define N_HR  ((long long)NIMG*HW*HW)     // 25165824
#define N_LR  ((long long)NIMG*OUTW*OUTW) // 1572864
#define NBLK  (NIMG*8)                    // 768 blocks, one = (img, 16 out rows)

// PyTorch bicubic kernel, a = -0.75
__device__ __forceinline__ float cubic075(float x){
    float ax = fabsf(x);
    float ax2 = ax*ax, ax3 = ax2*ax;
    const float A = -0.75f;
    float f1 = (A+2.f)*ax3 - (A+3.f)*ax2 + 1.f;
    float f2 = A*ax3 - 5.f*A*ax2 + 8.f*A*ax - 4.f*A;
    return ax <= 1.f ? f1 : (ax < 2.f ? f2 : 0.f);
}

// scale=4 antialiased window: 16 taps, dist=(k-7.5)/4, normalized.
// Shift-invariant across all output positions (absmax=0.0 in R1-R4).
__device__ __forceinline__ void get_weights(float w[16]){
    float s = 0.f;
#pragma unroll
    for (int k = 0; k < 16; ++k){
        float d = ((float)k - 7.5f) * 0.25f;
        w[k] = cubic075(d);
        s += w[k];
    }
#pragma unroll
    for (int k = 0; k < 16; ++k) w[k] /= s;
}

// Fused single-pass: block = (img, 16 out rows). 4 waves; wave w streams
// input rows j = 4i+w, i=0..18 (rows s..s+75, 1.19x halo). Depth-2 rotating
// prefetch on pred AND tgt. H-filter in-register via shuffles. Vertical via
// 32-row LDS ring, ONE barrier per iteration (WAR-disjoint by 16 rows).
__global__ __launch_bounds__(256, 3) void kmain(const float* __restrict__ pred,
                                                const float* __restrict__ tgt,
                                                const float* __restrict__ lr,
                                                double* __restrict__ part1,
                                                double* __restrict__ part2){
    const int b   = blockIdx.x;
    const int W   = ((b & 7) * (NBLK/8)) + (b >> 3);  // XCD owns 12 contiguous imgs
    const int img = W >> 3;
    const int grp = W & 7;
    const int o0  = grp << 4;                 // first output row
    const int s   = (o0 << 2) - 6;            // first (unclamped) input row
    const int tid = threadIdx.x;
    const int w   = tid >> 6;
    const int l   = tid & 63;

    __shared__ float  ring[32][128];          // 16 KB h-filtered row ring
    __shared__ double sred[8];

    float wt[16]; get_weights(wt);
    const float* P = pred + (size_t)img * (HW*HW);
    const float* T = tgt  + (size_t)img * (HW*HW);
    const float* L = lr   + (size_t)img * (OUTW*OUTW);

    float pix_acc = 0.f, lr_acc = 0.f;

    // pred pipeline prefill (rows for i=0 and i=1)
    int r0 = min(HW-1, max(0, s + w));
    int r1 = min(HW-1, max(0, s + 4 + w));
    const float4* rp0 = (const float4*)(P + (size_t)r0 * HW);
    const float4* rp1 = (const float4*)(P + (size_t)r1 * HW);
    float4 c0 = rp0[2*l], c1 = rp0[2*l+1];
    float4 n0 = rp1[2*l], n1 = rp1[2*l+1];
    // tgt pipeline prefill: first owned iter is i=1 (j=4+w) for w>=2
    float4 tc0, tc1, tn0, tn1;
    if (w >= 2){
        const float4* tp = (const float4*)(T + (size_t)(s + 4 + w) * HW);
        tn0 = tp[2*l]; tn1 = tp[2*l+1];
    }

    for (int i = 0; i < 19; ++i){
        const int jcur = 4*i + w;
        const int j2   = jcur + 8;            // row consumed at i+2
        // issue prefetches first (max load->use distance)
        float4 f0, f1, tf0, tf1;
        if (i < 17){
            int rn = min(HW-1, max(0, s + j2));
            const float4* rp = (const float4*)(P + (size_t)rn * HW);
            f0 = rp[2*l]; f1 = rp[2*l+1];
        }
        if (j2 < 70){                         // j2 >= 8 > 6 always; owned window
            const float4* tp = (const float4*)(T + (size_t)(s + j2) * HW);
            tf0 = tp[2*l]; tf1 = tp[2*l+1];
        }

        const float p0=c0.x,p1v=c0.y,p2v=c0.z,p3=c0.w,
                    p4=c1.x,p5=c1.y,p6=c1.z,p7=c1.w;

        // pix term: block owns input rows s+6 .. s+69
        if (jcur >= 6 && jcur < 70){
            pix_acc += fabsf(p0-tc0.x)+fabsf(p1v-tc0.y)+fabsf(p2v-tc0.z)+fabsf(p3-tc0.w)
                     + fabsf(p4-tc1.x)+fabsf(p5-tc1.y)+fabsf(p6-tc1.z)+fabsf(p7-tc1.w);
        }

        // horizontal halo via shuffles: cols 8l-6..8l-1 and 8l+8..8l+13
        float Lm6 = __shfl_up(p2v,1,64), Lm5 = __shfl_up(p3,1,64),
              Lm4 = __shfl_up(p4,1,64),  Lm3 = __shfl_up(p5,1,64),
              Lm2 = __shfl_up(p6,1,64),  Lm1 = __shfl_up(p7,1,64);
        float R8  = __shfl_down(p0,1,64), R9  = __shfl_down(p1v,1,64),
              R10 = __shfl_down(p2v,1,64),R11 = __shfl_down(p3,1,64),
              R12 = __shfl_down(p4,1,64), R13 = __shfl_down(p5,1,64);
        if (l == 0){ Lm6=p0; Lm5=p0; Lm4=p0; Lm3=p0; Lm2=p0; Lm1=p0; }
        if (l == 63){ R8=p7; R9=p7; R10=p7; R11=p7; R12=p7; R13=p7; }

        float w20[20] = {Lm6,Lm5,Lm4,Lm3,Lm2,Lm1,p0,p1v,p2v,p3,p4,p5,p6,p7,
                         R8,R9,R10,R11,R12,R13};
        float h0 = 0.f, h1 = 0.f;
#pragma unroll
        for (int k = 0; k < 16; ++k){
            h0 += wt[k]*w20[k];
            h1 += wt[k]*w20[k+4];
        }
        float2 st; st.x = h0; st.y = h1;
        *(float2*)&ring[jcur & 31][2*l] = st;

        __syncthreads();   // writes of iter i visible; WAR-safe vs iter i+1

        if (i >= 3 && tid < 128){
            const int q = i - 3;              // local output row 0..15
            float acc = 0.f;
#pragma unroll
            for (int r = 0; r < 16; ++r)
                acc += wt[r] * ring[(4*q + r) & 31][tid];
            lr_acc += fabsf(acc - L[(size_t)(o0 + q) * OUTW + tid]);
        }

        // rotate pipelines
        c0=n0; c1=n1; n0=f0; n1=f1;
        tc0=tn0; tc1=tn1; tn0=tf0; tn1=tf1;
    }

    // block reduction -> unique slots (no atomics, no init kernel)
#pragma unroll
    for (int off = 32; off > 0; off >>= 1){
        pix_acc += __shfl_down(pix_acc, off, 64);
        lr_acc  += __shfl_down(lr_acc,  off, 64);
    }
    if (l == 0){ sred[w] = (double)pix_acc; sred[4+w] = (double)lr_acc; }
    __syncthreads();
    if (tid == 0)  part1[b] = sred[0]+sred[1]+sred[2]+sred[3];
    if (tid == 64) part2[b] = sred[4]+sred[5]+sred[6]+sred[7];
}

__global__ __launch_bounds__(256) void k3(const double* __restrict__ part1,
                                          const double* __restrict__ part2,
                                          float* __restrict__ out){
    const int t = threadIdx.x;
    double v1 = 0.0, v2 = 0.0;
    for (int i = t; i < NBLK; i += 256){
        v1 += part1[i];
        v2 += part2[i];
    }
#pragma unroll
    for (int off = 32; off > 0; off >>= 1){
        v1 += __shfl_down(v1, off, 64);
        v2 += __shfl_down(v2, off, 64);
    }
    __shared__ double s1[4], s2[4];
    const int lane = t & 63, wid = t >> 6;
    if (lane == 0){ s1[wid] = v1; s2[wid] = v2; }
    __syncthreads();
    if (t == 0){
        double S1 = s1[0]+s1[1]+s1[2]+s1[3];
        double S2 = s2[0]+s2[1]+s2[2]+s2[3];
        float pix     = (float)(S1 / (double)N_HR);
        float lr_term = (float)(S2 / (double)N_LR);
        float pair    = 0.f;
        float consist = 1.0f * lr_term + 1.0f * pair;   // LAM_LR, LAM_PAIR
        float total   = pix + 0.1f * consist;           // LAM_CONSIST
        out[0] = total; out[1] = pix; out[2] = consist; out[3] = lr_term; out[4] = pair;
    }
}

extern "C" void kernel_launch(void* const* d_in, const int* in_sizes, int n_in,
                              void* d_out, int out_size, void* d_ws, size_t ws_size,
                              hipStream_t stream){
    const float* pred = (const float*)d_in[0];
    const float* tgt  = (const float*)d_in[1];
    const float* lrr  = (const float*)d_in[2];
    float* out = (float*)d_out;

    double* part1 = (double*)d_ws;        // 768 doubles, all written
    double* part2 = part1 + NBLK;         // 768 doubles, all written

    kmain<<<NBLK, 256, 0, stream>>>(pred, tgt, lrr, part1, part2);
    k3<<<1, 256, 0, stream>>>(part1, part2, out);
}